// Round 1
// baseline (341.882 us; speedup 1.0000x reference)
//
#include <hip/hip_runtime.h>
#include <hip/hip_bf16.h>
#include <stdint.h>

#define B_   4
#define H_   16
#define L_   2048
#define D_   64
#define QBLK 128
#define KVBLK 64
#define LDSPAD 72   // row stride in bf16 elems (64 + 8) -> 144 B rows, 2-way bank alias (free)

typedef __attribute__((ext_vector_type(8))) short bf16x8;
typedef __attribute__((ext_vector_type(4))) float f32x4;

__device__ __forceinline__ ushort f2bf(float f) {
  union { float f; uint32_t u; } x; x.f = f;
  uint32_t r = x.u + 0x7FFFu + ((x.u >> 16) & 1u);
  return (ushort)(r >> 16);
}

__global__ __launch_bounds__(256, 2)
void attn_fwd(const float* __restrict__ Q, const float* __restrict__ K,
              const float* __restrict__ V, const int* __restrict__ Mask,
              float* __restrict__ O)
{
  __shared__ ushort K_lds[KVBLK * LDSPAD];
  __shared__ ushort Vt_lds[D_ * LDSPAD];
  __shared__ ushort P_lds[4 * 16 * LDSPAD];
  __shared__ float  m_lds[KVBLK];

  const int tid  = threadIdx.x;
  const int wid  = tid >> 6;
  const int lane = tid & 63;
  const int lr   = lane & 15;   // row-within-16 (also C/D col)
  const int lg   = lane >> 4;   // 4-lane-group id 0..3

  const int bid = blockIdx.x;
  const int qt  = bid & 15;     // 2048/128 = 16 q-tiles
  const int bh  = bid >> 4;     // b*H + h, 0..63
  const int b   = bh >> 4;      // H = 16

  const float* Qg = Q + (size_t)bh * L_ * D_;
  const float* Kg = K + (size_t)bh * L_ * D_;
  const float* Vg = V + (size_t)bh * L_ * D_;
  const int*   Mg = Mask + (size_t)b * L_;
  float*       Og = O + (size_t)bh * L_ * D_;

  const int qbase = qt * QBLK + wid * 32;
  const float LOG2E = 1.4426950408889634f;

  // ---- Q fragments (persistent in registers) ----
  bf16x8 qf[2][2];
#pragma unroll
  for (int g = 0; g < 2; ++g)
#pragma unroll
    for (int c = 0; c < 2; ++c) {
      const float* src = Qg + (size_t)(qbase + g * 16 + lr) * D_ + lg * 8 + c * 32;
      float4 a = *(const float4*)(src);
      float4 bv = *(const float4*)(src + 4);
      bf16x8 q;
      q[0] = f2bf(a.x);  q[1] = f2bf(a.y);  q[2] = f2bf(a.z);  q[3] = f2bf(a.w);
      q[4] = f2bf(bv.x); q[5] = f2bf(bv.y); q[6] = f2bf(bv.z); q[7] = f2bf(bv.w);
      qf[g][c] = q;
    }

  f32x4 o_acc[2][4];
  float m_run[2][4], l_run[2][4];
#pragma unroll
  for (int g = 0; g < 2; ++g)
#pragma unroll
    for (int dt = 0; dt < 4; ++dt) {
      o_acc[g][dt] = (f32x4){0.f, 0.f, 0.f, 0.f};
    }
#pragma unroll
  for (int g = 0; g < 2; ++g)
#pragma unroll
    for (int r = 0; r < 4; ++r) { m_run[g][r] = -INFINITY; l_run[g][r] = 0.f; }

  ushort* Pw = P_lds + wid * 16 * LDSPAD;

  for (int k0 = 0; k0 < L_; k0 += KVBLK) {
    __syncthreads();
    // ---- stage K (row-major bf16) and V^T into LDS, coalesced float4 global reads ----
#pragma unroll
    for (int p = 0; p < 4; ++p) {
      int idx = p * 256 + tid;          // 0..1023 float4 slots of the 64x64 tile
      int row = idx >> 4;
      int c4  = idx & 15;
      const float4 kv = *(const float4*)(Kg + (size_t)(k0 + row) * D_ + c4 * 4);
      ushort* dst = K_lds + row * LDSPAD + c4 * 4;
      dst[0] = f2bf(kv.x); dst[1] = f2bf(kv.y); dst[2] = f2bf(kv.z); dst[3] = f2bf(kv.w);
      const float4 vv = *(const float4*)(Vg + (size_t)(k0 + row) * D_ + c4 * 4);
      int d0 = c4 * 4;
      Vt_lds[(d0 + 0) * LDSPAD + row] = f2bf(vv.x);
      Vt_lds[(d0 + 1) * LDSPAD + row] = f2bf(vv.y);
      Vt_lds[(d0 + 2) * LDSPAD + row] = f2bf(vv.z);
      Vt_lds[(d0 + 3) * LDSPAD + row] = f2bf(vv.w);
    }
    if (tid < KVBLK) m_lds[tid] = (Mg[k0 + tid] != 0) ? 1.0f : 0.0f;
    __syncthreads();

    // ---- K fragments, shared by both row-groups ----
    bf16x8 kf[4][2];
#pragma unroll
    for (int t = 0; t < 4; ++t)
#pragma unroll
      for (int c = 0; c < 2; ++c)
        kf[t][c] = *(const bf16x8*)(K_lds + (t * 16 + lr) * LDSPAD + lg * 8 + c * 32);

    float mk[4];
#pragma unroll
    for (int t = 0; t < 4; ++t) mk[t] = m_lds[t * 16 + lr];

#pragma unroll
    for (int g = 0; g < 2; ++g) {
      // ---- S = Q K^T (16 x 64) ----
      f32x4 s[4];
#pragma unroll
      for (int t = 0; t < 4; ++t) s[t] = (f32x4){0.f, 0.f, 0.f, 0.f};
#pragma unroll
      for (int c = 0; c < 2; ++c)
#pragma unroll
        for (int t = 0; t < 4; ++t)
          s[t] = __builtin_amdgcn_mfma_f32_16x16x32_bf16(qf[g][c], kf[t][c], s[t], 0, 0, 0);

      // ---- scale + mask, tile row-max ----
      float sv[4][4];
      float mt[4] = {-INFINITY, -INFINITY, -INFINITY, -INFINITY};
#pragma unroll
      for (int t = 0; t < 4; ++t)
#pragma unroll
        for (int r = 0; r < 4; ++r) {
          float x = s[t][r] * 0.125f;
          x = (mk[t] != 0.f) ? x : -1.0e9f;
          sv[t][r] = x;
          mt[r] = fmaxf(mt[r], x);
        }
#pragma unroll
      for (int r = 0; r < 4; ++r) {
        float v = mt[r];
        v = fmaxf(v, __shfl_xor(v, 1));
        v = fmaxf(v, __shfl_xor(v, 2));
        v = fmaxf(v, __shfl_xor(v, 4));
        v = fmaxf(v, __shfl_xor(v, 8));
        mt[r] = v;
      }

      float fac[4];
#pragma unroll
      for (int r = 0; r < 4; ++r) {
        float mn = fmaxf(m_run[g][r], mt[r]);
        fac[r] = __builtin_amdgcn_exp2f((m_run[g][r] - mn) * LOG2E);
        m_run[g][r] = mn;
      }

      float psum[4] = {0.f, 0.f, 0.f, 0.f};
#pragma unroll
      for (int t = 0; t < 4; ++t)
#pragma unroll
        for (int r = 0; r < 4; ++r) {
          float p = __builtin_amdgcn_exp2f((sv[t][r] - m_run[g][r]) * LOG2E);
          sv[t][r] = p;
          psum[r] += p;
        }
#pragma unroll
      for (int r = 0; r < 4; ++r) {
        float v = psum[r];
        v += __shfl_xor(v, 1);
        v += __shfl_xor(v, 2);
        v += __shfl_xor(v, 4);
        v += __shfl_xor(v, 8);
        l_run[g][r] = l_run[g][r] * fac[r] + v;
      }
#pragma unroll
      for (int dt = 0; dt < 4; ++dt)
#pragma unroll
        for (int r = 0; r < 4; ++r)
          o_acc[g][dt][r] *= fac[r];

      // ---- P -> LDS (re-fragment for PV A operand) ----
#pragma unroll
      for (int t = 0; t < 4; ++t)
#pragma unroll
        for (int r = 0; r < 4; ++r)
          Pw[(lg * 4 + r) * LDSPAD + t * 16 + lr] = f2bf(sv[t][r]);

      bf16x8 pa[2];
#pragma unroll
      for (int c = 0; c < 2; ++c)
        pa[c] = *(const bf16x8*)(Pw + lr * LDSPAD + lg * 8 + c * 32);

      // ---- O += P V ----
#pragma unroll
      for (int dt = 0; dt < 4; ++dt)
#pragma unroll
        for (int c = 0; c < 2; ++c) {
          bf16x8 vb = *(const bf16x8*)(Vt_lds + (dt * 16 + lr) * LDSPAD + lg * 8 + c * 32);
          o_acc[g][dt] = __builtin_amdgcn_mfma_f32_16x16x32_bf16(pa[c], vb, o_acc[g][dt], 0, 0, 0);
        }
    }
  }

  // ---- epilogue: O / l ----
#pragma unroll
  for (int g = 0; g < 2; ++g) {
    float inv[4];
#pragma unroll
    for (int r = 0; r < 4; ++r) inv[r] = 1.0f / l_run[g][r];
#pragma unroll
    for (int dt = 0; dt < 4; ++dt)
#pragma unroll
      for (int r = 0; r < 4; ++r) {
        int row = qbase + g * 16 + lg * 4 + r;
        Og[(size_t)row * D_ + dt * 16 + lr] = o_acc[g][dt][r] * inv[r];
      }
  }
}

extern "C" void kernel_launch(void* const* d_in, const int* in_sizes, int n_in,
                              void* d_out, int out_size, void* d_ws, size_t ws_size,
                              hipStream_t stream) {
  const float* Q = (const float*)d_in[0];
  const float* K = (const float*)d_in[1];
  const float* V = (const float*)d_in[2];
  const int*   M = (const int*)d_in[3];
  float*       O = (float*)d_out;
  dim3 grid(B_ * H_ * (L_ / QBLK));
  attn_fwd<<<grid, dim3(256), 0, stream>>>(Q, K, V, M, O);
}

// Round 2
// 132.420 us; speedup vs baseline: 2.5818x; 2.5818x over previous
//
#include <hip/hip_runtime.h>
#include <hip/hip_bf16.h>
#include <stdint.h>

#define B_    4
#define H_    16
#define L_    2048
#define D_    64
#define BH_   64
#define NT_   32      // KV tiles of 64
#define QBLK  128
#define KVBLK 64

typedef __attribute__((ext_vector_type(8))) short bf16x8;
typedef __attribute__((ext_vector_type(8))) unsigned short ushort8;
typedef __attribute__((ext_vector_type(4))) unsigned short ushort4v;
typedef __attribute__((ext_vector_type(4))) float f32x4;

__device__ __forceinline__ ushort f2bf(float f) {
  union { float f; uint32_t u; } x; x.f = f;
  uint32_t r = x.u + 0x7FFFu + ((x.u >> 16) & 1u);
  return (ushort)(r >> 16);
}

__device__ __forceinline__ uint32_t pkbf(float lo, float hi) {
  uint32_t r;
  asm("v_cvt_pk_bf16_f32 %0, %1, %2" : "=v"(r) : "v"(lo), "v"(hi));
  return r;
}

// ---------------- pre-pass: fp32 -> bf16, tiled + permuted + swizzled ----------------
// Kp tile (bh,kt): elem(row,d) at row*64 + (d ^ ((row&7)<<3))            (row = k within tile)
// Vtp tile: elem(d,pos) at d*64 + (pos ^ ((d&7)<<3)), holding V[k(pos)][d],
//   pos = 32c+8lg+4b+a  <->  k = 32c+16b+4lg+a   (matches MFMA A-frag slot order)
__global__ __launch_bounds__(256, 2)
void prep_kv(const float* __restrict__ K, const float* __restrict__ V,
             ushort* __restrict__ Kp, ushort* __restrict__ Vtp)
{
  __shared__ ushort Vl[64 * 68];   // stride 68: 4-way-max gather conflicts
  const int bid = blockIdx.x;      // bh*32 + kt
  const int tid = threadIdx.x;
  const float* Kg = K + (size_t)bid * 4096;
  const float* Vg = V + (size_t)bid * 4096;
  ushort* Kt = Kp + (size_t)bid * 4096;
  ushort* Vt = Vtp + (size_t)bid * 4096;

#pragma unroll
  for (int j = 0; j < 2; ++j) {
    int chunk = j * 256 + tid;
    int row = chunk >> 3, d8 = chunk & 7;
    const float* s = Kg + row * 64 + d8 * 8;
    float4 a = *(const float4*)s, b2 = *(const float4*)(s + 4);
    ushort8 o;
    o[0]=f2bf(a.x); o[1]=f2bf(a.y); o[2]=f2bf(a.z); o[3]=f2bf(a.w);
    o[4]=f2bf(b2.x);o[5]=f2bf(b2.y);o[6]=f2bf(b2.z);o[7]=f2bf(b2.w);
    *(ushort8*)(Kt + row * 64 + ((d8 * 8) ^ ((row & 7) << 3))) = o;

    const float* sv = Vg + row * 64 + d8 * 8;
    float4 va = *(const float4*)sv, vb2 = *(const float4*)(sv + 4);
    ushort4v w0, w1;
    w0[0]=f2bf(va.x); w0[1]=f2bf(va.y); w0[2]=f2bf(va.z); w0[3]=f2bf(va.w);
    w1[0]=f2bf(vb2.x);w1[1]=f2bf(vb2.y);w1[2]=f2bf(vb2.z);w1[3]=f2bf(vb2.w);
    *(ushort4v*)(&Vl[row * 68 + d8 * 8])     = w0;
    *(ushort4v*)(&Vl[row * 68 + d8 * 8 + 4]) = w1;
  }
  __syncthreads();
#pragma unroll
  for (int j = 0; j < 2; ++j) {
    int chunk = j * 256 + tid;
    int d = chunk >> 3, p8 = chunk & 7;
    ushort8 o;
#pragma unroll
    for (int e = 0; e < 8; ++e) {
      int pos = p8 * 8 + e;
      int c = pos >> 5, lgv = (pos >> 3) & 3, bb = (pos >> 2) & 1, aa = pos & 3;
      int kk = 32 * c + 16 * bb + 4 * lgv + aa;
      o[e] = Vl[kk * 68 + d];
    }
    *(ushort8*)(Vt + d * 64 + ((p8 * 8) ^ ((d & 7) << 3))) = o;
  }
}

// ---------------- main attention kernel ----------------
__global__ __launch_bounds__(256, 3)
void attn_fwd2(const float* __restrict__ Q, const int* __restrict__ Mask,
               const ushort* __restrict__ Kp, const ushort* __restrict__ Vtp,
               float* __restrict__ O)
{
  __shared__ ushort Kb[2][4096];
  __shared__ ushort Vb[2][4096];
  __shared__ float  mb[2][64];

  const int tid  = threadIdx.x;
  const int wid  = tid >> 6;
  const int lane = tid & 63;
  const int lr   = lane & 15;
  const int lg   = lane >> 4;

  const int bid = blockIdx.x;
  const int qt  = bid & 15;
  const int bh  = bid >> 4;
  const int b   = bh >> 4;

  const float* Qg = Q + (size_t)bh * L_ * D_;
  const int*   Mg = Mask + (size_t)b * L_;
  float*       Og = O + (size_t)bh * L_ * D_;
  const ushort* Kbase = Kp  + (size_t)bh * 131072;
  const ushort* Vbase = Vtp + (size_t)bh * 131072;

  const int qbase = qt * QBLK + wid * 32;
  const float qscale = 0.125f * 1.4426950408889634f;  // scale * log2(e): exp2-domain

  // Q fragments (scaled, bf16, persistent)
  bf16x8 qf[2][2];
#pragma unroll
  for (int g = 0; g < 2; ++g)
#pragma unroll
    for (int c = 0; c < 2; ++c) {
      const float* src = Qg + (size_t)(qbase + g * 16 + lr) * D_ + c * 32 + lg * 8;
      float4 a = *(const float4*)src, b2 = *(const float4*)(src + 4);
      bf16x8 q;
      q[0]=f2bf(a.x*qscale);  q[1]=f2bf(a.y*qscale);  q[2]=f2bf(a.z*qscale);  q[3]=f2bf(a.w*qscale);
      q[4]=f2bf(b2.x*qscale); q[5]=f2bf(b2.y*qscale); q[6]=f2bf(b2.z*qscale); q[7]=f2bf(b2.w*qscale);
      qf[g][c] = q;
    }

  f32x4 o_acc[2][4];
#pragma unroll
  for (int g = 0; g < 2; ++g)
#pragma unroll
    for (int dt = 0; dt < 4; ++dt) o_acc[g][dt] = (f32x4){0.f,0.f,0.f,0.f};
  float m_run0 = -INFINITY, m_run1 = -INFINITY, l_run0 = 0.f, l_run1 = 0.f;

  // prologue: load tile 0 into regs
  ushort8 rk0, rk1, rv0, rv1; float rmf = 0.f;
  {
    const ushort* Ks = Kbase;
    const ushort* Vs = Vbase;
    rk0 = *(const ushort8*)(Ks + tid * 8);
    rk1 = *(const ushort8*)(Ks + 2048 + tid * 8);
    rv0 = *(const ushort8*)(Vs + tid * 8);
    rv1 = *(const ushort8*)(Vs + 2048 + tid * 8);
    if (tid < 64) rmf = (Mg[tid] != 0) ? 1.f : 0.f;
  }

  int cur = 0;
  for (int kt = 0; kt < NT_; ++kt) {
    // write staged regs -> buf[cur]
    *(ushort8*)(&Kb[cur][tid * 8])        = rk0;
    *(ushort8*)(&Kb[cur][2048 + tid * 8]) = rk1;
    *(ushort8*)(&Vb[cur][tid * 8])        = rv0;
    *(ushort8*)(&Vb[cur][2048 + tid * 8]) = rv1;
    if (tid < 64) mb[cur][tid] = rmf;

    // T14: issue next tile's global loads (hidden under compute)
    if (kt + 1 < NT_) {
      const ushort* Ks = Kbase + (size_t)(kt + 1) * 4096;
      const ushort* Vs = Vbase + (size_t)(kt + 1) * 4096;
      rk0 = *(const ushort8*)(Ks + tid * 8);
      rk1 = *(const ushort8*)(Ks + 2048 + tid * 8);
      rv0 = *(const ushort8*)(Vs + tid * 8);
      rv1 = *(const ushort8*)(Vs + 2048 + tid * 8);
      if (tid < 64) rmf = (Mg[(kt + 1) * 64 + tid] != 0) ? 1.f : 0.f;
    }
    __syncthreads();   // publish buf[cur]

    const ushort* Kc = Kb[cur];
    const ushort* Vc = Vb[cur];
    const float*  mc = mb[cur];

    // mask flags: k = 16t + 4lg + r
    f32x4 mf[4];
#pragma unroll
    for (int t = 0; t < 4; ++t) mf[t] = *(const f32x4*)(mc + 16 * t + 4 * lg);

    // ---- S^T = K Q^T (swapped): lane holds S[k=16t+4lg+r][q=lr] ----
    f32x4 st0[4], st1[4];
#pragma unroll
    for (int t = 0; t < 4; ++t) { st0[t] = (f32x4){0,0,0,0}; st1[t] = (f32x4){0,0,0,0}; }
#pragma unroll
    for (int c = 0; c < 2; ++c) {
      bf16x8 kf[4];
#pragma unroll
      for (int t = 0; t < 4; ++t)
        kf[t] = *(const bf16x8*)(Kc + (16 * t + lr) * 64 + ((c * 32 + lg * 8) ^ ((lr & 7) << 3)));
#pragma unroll
      for (int t = 0; t < 4; ++t) st0[t] = __builtin_amdgcn_mfma_f32_16x16x32_bf16(kf[t], qf[0][c], st0[t], 0, 0, 0);
#pragma unroll
      for (int t = 0; t < 4; ++t) st1[t] = __builtin_amdgcn_mfma_f32_16x16x32_bf16(kf[t], qf[1][c], st1[t], 0, 0, 0);
    }

    uint32_t pkg[2][4][2];
    // ---- online softmax, fully in-register (exp2 domain) ----
#pragma unroll
    for (int g = 0; g < 2; ++g) {
      float x[4][4];
      float mt = -INFINITY;
#pragma unroll
      for (int t = 0; t < 4; ++t)
#pragma unroll
        for (int r = 0; r < 4; ++r) {
          float v = (g == 0) ? st0[t][r] : st1[t][r];
          v = (mf[t][r] != 0.f) ? v : -1.0e9f;
          x[t][r] = v;
          mt = fmaxf(mt, v);
        }
      mt = fmaxf(mt, __shfl_xor(mt, 16));
      mt = fmaxf(mt, __shfl_xor(mt, 32));
      float m_old = (g == 0) ? m_run0 : m_run1;
      float mnew = fmaxf(m_old, mt);
      float fac = __builtin_amdgcn_exp2f(m_old - mnew);
      float sum = 0.f;
#pragma unroll
      for (int t = 0; t < 4; ++t)
#pragma unroll
        for (int r = 0; r < 4; ++r) {
          float p = __builtin_amdgcn_exp2f(x[t][r] - mnew);
          x[t][r] = p;
          sum += p;
        }
      sum += __shfl_xor(sum, 16);
      sum += __shfl_xor(sum, 32);
      if (g == 0) { l_run0 = l_run0 * fac + sum; m_run0 = mnew; }
      else        { l_run1 = l_run1 * fac + sum; m_run1 = mnew; }
      // rescale O (o rows are q = 4lg+r -> fetch fac from lane with lr' = 4lg+r)
      float fq[4];
#pragma unroll
      for (int r = 0; r < 4; ++r) fq[r] = __shfl(fac, 20 * lg + r);
#pragma unroll
      for (int dt = 0; dt < 4; ++dt)
#pragma unroll
        for (int r = 0; r < 4; ++r) o_acc[g][dt][r] *= fq[r];
      // pack P to bf16 pairs (k = 16t+4lg+{2r2,2r2+1})
#pragma unroll
      for (int t = 0; t < 4; ++t)
#pragma unroll
        for (int r2 = 0; r2 < 2; ++r2) pkg[g][t][r2] = pkbf(x[t][2 * r2], x[t][2 * r2 + 1]);
    }

    // ---- O += P V : A-frag = own lane's pk words (k-order matches Vtp permutation) ----
#pragma unroll
    for (int dt = 0; dt < 4; ++dt)
#pragma unroll
      for (int c = 0; c < 2; ++c) {
        bf16x8 vb = *(const bf16x8*)(Vc + (16 * dt + lr) * 64 + ((c * 32 + lg * 8) ^ ((lr & 7) << 3)));
        union { uint32_t u[4]; bf16x8 v; } pa0, pa1;
        pa0.u[0] = pkg[0][2*c][0]; pa0.u[1] = pkg[0][2*c][1];
        pa0.u[2] = pkg[0][2*c+1][0]; pa0.u[3] = pkg[0][2*c+1][1];
        pa1.u[0] = pkg[1][2*c][0]; pa1.u[1] = pkg[1][2*c][1];
        pa1.u[2] = pkg[1][2*c+1][0]; pa1.u[3] = pkg[1][2*c+1][1];
        o_acc[0][dt] = __builtin_amdgcn_mfma_f32_16x16x32_bf16(pa0.v, vb, o_acc[0][dt], 0, 0, 0);
        o_acc[1][dt] = __builtin_amdgcn_mfma_f32_16x16x32_bf16(pa1.v, vb, o_acc[1][dt], 0, 0, 0);
      }
    cur ^= 1;
  }

  // ---- epilogue ----
#pragma unroll
  for (int g = 0; g < 2; ++g) {
    float l_mine = (g == 0) ? l_run0 : l_run1;
    float inv[4];
#pragma unroll
    for (int r = 0; r < 4; ++r) {
      float lq = __shfl(l_mine, 20 * lg + r);
      inv[r] = 1.0f / lq;
    }
#pragma unroll
    for (int dt = 0; dt < 4; ++dt)
#pragma unroll
      for (int r = 0; r < 4; ++r) {
        int row = qbase + g * 16 + 4 * lg + r;
        Og[(size_t)row * D_ + dt * 16 + lr] = o_acc[g][dt][r] * inv[r];
      }
  }
}

// ---------------- fallback (round-1, proven) if workspace too small ----------------
#define LDSPAD 72
__global__ __launch_bounds__(256, 2)
void attn_fwd_v1(const float* __restrict__ Q, const float* __restrict__ K,
                 const float* __restrict__ V, const int* __restrict__ Mask,
                 float* __restrict__ O)
{
  __shared__ ushort K_lds[KVBLK * LDSPAD];
  __shared__ ushort Vt_lds[D_ * LDSPAD];
  __shared__ ushort P_lds[4 * 16 * LDSPAD];
  __shared__ float  m_lds[KVBLK];

  const int tid  = threadIdx.x;
  const int wid  = tid >> 6;
  const int lane = tid & 63;
  const int lr   = lane & 15;
  const int lg   = lane >> 4;

  const int bid = blockIdx.x;
  const int qt  = bid & 15;
  const int bh  = bid >> 4;
  const int b   = bh >> 4;

  const float* Qg = Q + (size_t)bh * L_ * D_;
  const float* Kg = K + (size_t)bh * L_ * D_;
  const float* Vg = V + (size_t)bh * L_ * D_;
  const int*   Mg = Mask + (size_t)b * L_;
  float*       Og = O + (size_t)bh * L_ * D_;

  const int qbase = qt * QBLK + wid * 32;
  const float LOG2E = 1.4426950408889634f;

  bf16x8 qf[2][2];
#pragma unroll
  for (int g = 0; g < 2; ++g)
#pragma unroll
    for (int c = 0; c < 2; ++c) {
      const float* src = Qg + (size_t)(qbase + g * 16 + lr) * D_ + lg * 8 + c * 32;
      float4 a = *(const float4*)(src);
      float4 bv = *(const float4*)(src + 4);
      bf16x8 q;
      q[0]=f2bf(a.x); q[1]=f2bf(a.y); q[2]=f2bf(a.z); q[3]=f2bf(a.w);
      q[4]=f2bf(bv.x);q[5]=f2bf(bv.y);q[6]=f2bf(bv.z);q[7]=f2bf(bv.w);
      qf[g][c] = q;
    }

  f32x4 o_acc[2][4];
  float m_run[2][4], l_run[2][4];
#pragma unroll
  for (int g = 0; g < 2; ++g)
#pragma unroll
    for (int dt = 0; dt < 4; ++dt) o_acc[g][dt] = (f32x4){0.f,0.f,0.f,0.f};
#pragma unroll
  for (int g = 0; g < 2; ++g)
#pragma unroll
    for (int r = 0; r < 4; ++r) { m_run[g][r] = -INFINITY; l_run[g][r] = 0.f; }

  ushort* Pw = P_lds + wid * 16 * LDSPAD;

  for (int k0 = 0; k0 < L_; k0 += KVBLK) {
    __syncthreads();
#pragma unroll
    for (int p = 0; p < 4; ++p) {
      int idx = p * 256 + tid;
      int row = idx >> 4;
      int c4  = idx & 15;
      const float4 kv = *(const float4*)(Kg + (size_t)(k0 + row) * D_ + c4 * 4);
      ushort* dst = K_lds + row * LDSPAD + c4 * 4;
      dst[0]=f2bf(kv.x); dst[1]=f2bf(kv.y); dst[2]=f2bf(kv.z); dst[3]=f2bf(kv.w);
      const float4 vv = *(const float4*)(Vg + (size_t)(k0 + row) * D_ + c4 * 4);
      int d0 = c4 * 4;
      Vt_lds[(d0+0)*LDSPAD + row] = f2bf(vv.x);
      Vt_lds[(d0+1)*LDSPAD + row] = f2bf(vv.y);
      Vt_lds[(d0+2)*LDSPAD + row] = f2bf(vv.z);
      Vt_lds[(d0+3)*LDSPAD + row] = f2bf(vv.w);
    }
    if (tid < KVBLK) m_lds[tid] = (Mg[k0 + tid] != 0) ? 1.0f : 0.0f;
    __syncthreads();

    bf16x8 kf[4][2];
#pragma unroll
    for (int t = 0; t < 4; ++t)
#pragma unroll
      for (int c = 0; c < 2; ++c)
        kf[t][c] = *(const bf16x8*)(K_lds + (t * 16 + lr) * LDSPAD + lg * 8 + c * 32);

    float mk[4];
#pragma unroll
    for (int t = 0; t < 4; ++t) mk[t] = m_lds[t * 16 + lr];

#pragma unroll
    for (int g = 0; g < 2; ++g) {
      f32x4 s[4];
#pragma unroll
      for (int t = 0; t < 4; ++t) s[t] = (f32x4){0.f,0.f,0.f,0.f};
#pragma unroll
      for (int c = 0; c < 2; ++c)
#pragma unroll
        for (int t = 0; t < 4; ++t)
          s[t] = __builtin_amdgcn_mfma_f32_16x16x32_bf16(qf[g][c], kf[t][c], s[t], 0, 0, 0);

      float sv[4][4];
      float mt[4] = {-INFINITY,-INFINITY,-INFINITY,-INFINITY};
#pragma unroll
      for (int t = 0; t < 4; ++t)
#pragma unroll
        for (int r = 0; r < 4; ++r) {
          float xx = s[t][r] * 0.125f;
          xx = (mk[t] != 0.f) ? xx : -1.0e9f;
          sv[t][r] = xx;
          mt[r] = fmaxf(mt[r], xx);
        }
#pragma unroll
      for (int r = 0; r < 4; ++r) {
        float v = mt[r];
        v = fmaxf(v, __shfl_xor(v, 1));
        v = fmaxf(v, __shfl_xor(v, 2));
        v = fmaxf(v, __shfl_xor(v, 4));
        v = fmaxf(v, __shfl_xor(v, 8));
        mt[r] = v;
      }
      float fac[4];
#pragma unroll
      for (int r = 0; r < 4; ++r) {
        float mn = fmaxf(m_run[g][r], mt[r]);
        fac[r] = __builtin_amdgcn_exp2f((m_run[g][r] - mn) * LOG2E);
        m_run[g][r] = mn;
      }
      float psum[4] = {0.f,0.f,0.f,0.f};
#pragma unroll
      for (int t = 0; t < 4; ++t)
#pragma unroll
        for (int r = 0; r < 4; ++r) {
          float p = __builtin_amdgcn_exp2f((sv[t][r] - m_run[g][r]) * LOG2E);
          sv[t][r] = p;
          psum[r] += p;
        }
#pragma unroll
      for (int r = 0; r < 4; ++r) {
        float v = psum[r];
        v += __shfl_xor(v, 1); v += __shfl_xor(v, 2);
        v += __shfl_xor(v, 4); v += __shfl_xor(v, 8);
        l_run[g][r] = l_run[g][r] * fac[r] + v;
      }
#pragma unroll
      for (int dt = 0; dt < 4; ++dt)
#pragma unroll
        for (int r = 0; r < 4; ++r) o_acc[g][dt][r] *= fac[r];
#pragma unroll
      for (int t = 0; t < 4; ++t)
#pragma unroll
        for (int r = 0; r < 4; ++r)
          Pw[(lg * 4 + r) * LDSPAD + t * 16 + lr] = f2bf(sv[t][r]);
      bf16x8 pa[2];
#pragma unroll
      for (int c = 0; c < 2; ++c)
        pa[c] = *(const bf16x8*)(Pw + lr * LDSPAD + lg * 8 + c * 32);
#pragma unroll
      for (int dt = 0; dt < 4; ++dt)
#pragma unroll
        for (int c = 0; c < 2; ++c) {
          bf16x8 vb = *(const bf16x8*)(Vt_lds + (dt * 16 + lr) * LDSPAD + lg * 8 + c * 32);
          o_acc[g][dt] = __builtin_amdgcn_mfma_f32_16x16x32_bf16(pa[c], vb, o_acc[g][dt], 0, 0, 0);
        }
    }
  }
#pragma unroll
  for (int g = 0; g < 2; ++g) {
    float inv[4];
#pragma unroll
    for (int r = 0; r < 4; ++r) inv[r] = 1.0f / l_run[g][r];
#pragma unroll
    for (int dt = 0; dt < 4; ++dt)
#pragma unroll
      for (int r = 0; r < 4; ++r) {
        int row = qbase + g * 16 + lg * 4 + r;
        Og[(size_t)row * D_ + dt * 16 + lr] = o_acc[g][dt][r] * inv[r];
      }
  }
}

extern "C" void kernel_launch(void* const* d_in, const int* in_sizes, int n_in,
                              void* d_out, int out_size, void* d_ws, size_t ws_size,
                              hipStream_t stream) {
  const float* Q = (const float*)d_in[0];
  const float* K = (const float*)d_in[1];
  const float* V = (const float*)d_in[2];
  const int*   M = (const int*)d_in[3];
  float*       O = (float*)d_out;

  const size_t elems = (size_t)BH_ * L_ * D_;            // 8,388,608
  if (ws_size >= 2 * elems * sizeof(ushort)) {
    ushort* Kp  = (ushort*)d_ws;
    ushort* Vtp = Kp + elems;
    prep_kv<<<dim3(BH_ * NT_), dim3(256), 0, stream>>>(K, V, Kp, Vtp);
    attn_fwd2<<<dim3(BH_ * (L_ / QBLK)), dim3(256), 0, stream>>>(Q, M, Kp, Vtp, O);
  } else {
    attn_fwd_v1<<<dim3(BH_ * (L_ / QBLK)), dim3(256), 0, stream>>>(Q, K, V, M, O);
  }
}

// Round 3
// 120.891 us; speedup vs baseline: 2.8280x; 1.0954x over previous
//
#include <hip/hip_runtime.h>
#include <hip/hip_bf16.h>
#include <stdint.h>

#define B_    4
#define H_    16
#define L_    2048
#define D_    64
#define BH_   64
#define NT_   32      // KV tiles of 64
#define KVBLK 64
#define MASKBIAS (-1.4426950408889634e9f)   // -1e9 * log2(e), exp2-domain

typedef __attribute__((ext_vector_type(8))) short bf16x8;
typedef __attribute__((ext_vector_type(8))) unsigned short ushort8;
typedef __attribute__((ext_vector_type(4))) unsigned short ushort4v;
typedef __attribute__((ext_vector_type(4))) float f32x4;

__device__ __forceinline__ ushort f2bf(float f) {
  union { float f; uint32_t u; } x; x.f = f;
  uint32_t r = x.u + 0x7FFFu + ((x.u >> 16) & 1u);
  return (ushort)(r >> 16);
}

__device__ __forceinline__ uint32_t pkbf(float lo, float hi) {
  uint32_t r;
  asm("v_cvt_pk_bf16_f32 %0, %1, %2" : "=v"(r) : "v"(lo), "v"(hi));
  return r;
}

// ---------------- pre-pass: fp32 -> bf16, tiled + permuted + swizzled ----------------
// Kp tile (bh,kt): elem(row,d) at row*64 + (d ^ ((row&7)<<3))
// Vtp tile: elem(d,pos) at d*64 + (pos ^ ((d&7)<<3)), holding V[k(pos)][d],
//   pos = 32c+8lg+4b+a  <->  k = 32c+16b+4lg+a  (MFMA A-frag slot order)
__global__ __launch_bounds__(256, 2)
void prep_kv(const float* __restrict__ K, const float* __restrict__ V,
             ushort* __restrict__ Kp, ushort* __restrict__ Vtp)
{
  __shared__ ushort Vl[64 * 68];
  const int bid = blockIdx.x;      // bh*32 + kt
  const int tid = threadIdx.x;
  const float* Kg = K + (size_t)bid * 4096;
  const float* Vg = V + (size_t)bid * 4096;
  ushort* Kt = Kp + (size_t)bid * 4096;
  ushort* Vt = Vtp + (size_t)bid * 4096;

#pragma unroll
  for (int j = 0; j < 2; ++j) {
    int chunk = j * 256 + tid;
    int row = chunk >> 3, d8 = chunk & 7;
    const float* s = Kg + row * 64 + d8 * 8;
    float4 a = *(const float4*)s, b2 = *(const float4*)(s + 4);
    ushort8 o;
    o[0]=f2bf(a.x); o[1]=f2bf(a.y); o[2]=f2bf(a.z); o[3]=f2bf(a.w);
    o[4]=f2bf(b2.x);o[5]=f2bf(b2.y);o[6]=f2bf(b2.z);o[7]=f2bf(b2.w);
    *(ushort8*)(Kt + row * 64 + ((d8 * 8) ^ ((row & 7) << 3))) = o;

    const float* sv = Vg + row * 64 + d8 * 8;
    float4 va = *(const float4*)sv, vb2 = *(const float4*)(sv + 4);
    ushort4v w0, w1;
    w0[0]=f2bf(va.x); w0[1]=f2bf(va.y); w0[2]=f2bf(va.z); w0[3]=f2bf(va.w);
    w1[0]=f2bf(vb2.x);w1[1]=f2bf(vb2.y);w1[2]=f2bf(vb2.z);w1[3]=f2bf(vb2.w);
    *(ushort4v*)(&Vl[row * 68 + d8 * 8])     = w0;
    *(ushort4v*)(&Vl[row * 68 + d8 * 8 + 4]) = w1;
  }
  __syncthreads();
#pragma unroll
  for (int j = 0; j < 2; ++j) {
    int chunk = j * 256 + tid;
    int d = chunk >> 3, p8 = chunk & 7;
    ushort8 o;
#pragma unroll
    for (int e = 0; e < 8; ++e) {
      int pos = p8 * 8 + e;
      int c = pos >> 5, lgv = (pos >> 3) & 3, bb = (pos >> 2) & 1, aa = pos & 3;
      int kk = 32 * c + 16 * bb + 4 * lgv + aa;
      o[e] = Vl[kk * 68 + d];
    }
    *(ushort8*)(Vt + d * 64 + ((p8 * 8) ^ ((d & 7) << 3))) = o;
  }
}

// ---------------- main attention kernel: 4 row-groups (64 q) per wave ----------------
__global__ __launch_bounds__(256, 2)
void attn_fwd3(const float* __restrict__ Q, const int* __restrict__ Mask,
               const ushort* __restrict__ Kp, const ushort* __restrict__ Vtp,
               float* __restrict__ O)
{
  __shared__ __align__(16) ushort Kb[2][4096];
  __shared__ __align__(16) ushort Vb[2][4096];
  __shared__ __align__(16) float  mb[2][64];

  const int tid  = threadIdx.x;
  const int wid  = tid >> 6;
  const int lane = tid & 63;
  const int lr   = lane & 15;
  const int lg   = lane >> 4;

  // XCD-aware mapping: all 8 q-tiles of a bh land on one XCD (bid%8 = XCD)
  const int x  = blockIdx.x;            // 0..511
  const int bh = (x & 7) * 8 + ((x >> 3) & 7);
  const int qt = x >> 6;                // 0..7
  const int b  = bh >> 4;

  const float* Qg = Q + (size_t)bh * L_ * D_;
  const int*   Mg = Mask + (size_t)b * L_;
  float*       Og = O + (size_t)bh * L_ * D_;
  const ushort* Kbase = Kp  + (size_t)bh * 131072;
  const ushort* Vbase = Vtp + (size_t)bh * 131072;

  const int qbase = qt * 256 + wid * 64;
  const float qscale = 0.125f * 1.4426950408889634f;  // scale * log2(e)

  // ---- Q fragments (scaled, bf16, persistent): 4 row-groups ----
  bf16x8 qf[4][2];
#pragma unroll
  for (int g = 0; g < 4; ++g)
#pragma unroll
    for (int c = 0; c < 2; ++c) {
      const float* src = Qg + (size_t)(qbase + g * 16 + lr) * D_ + c * 32 + lg * 8;
      float4 a = *(const float4*)src, b2 = *(const float4*)(src + 4);
      bf16x8 q;
      q[0]=f2bf(a.x*qscale);  q[1]=f2bf(a.y*qscale);  q[2]=f2bf(a.z*qscale);  q[3]=f2bf(a.w*qscale);
      q[4]=f2bf(b2.x*qscale); q[5]=f2bf(b2.y*qscale); q[6]=f2bf(b2.z*qscale); q[7]=f2bf(b2.w*qscale);
      qf[g][c] = q;
    }

  f32x4 o_acc[4][4];
#pragma unroll
  for (int g = 0; g < 4; ++g)
#pragma unroll
    for (int dt = 0; dt < 4; ++dt) o_acc[g][dt] = (f32x4){0.f,0.f,0.f,0.f};
  float m_run[4] = {-INFINITY,-INFINITY,-INFINITY,-INFINITY};
  float l_run[4] = {0.f,0.f,0.f,0.f};

  // ---- staging prologue: tile 0 -> regs (wave w covers 2KB of K and of V) ----
  ushort8 rk0, rk1, rv0, rv1; float rmf = 0.f;
  {
    const ushort* Ks = Kbase;
    const ushort* Vs = Vbase;
    rk0 = *(const ushort8*)(Ks + wid * 1024 + lane * 8);
    rk1 = *(const ushort8*)(Ks + wid * 1024 + 512 + lane * 8);
    rv0 = *(const ushort8*)(Vs + wid * 1024 + lane * 8);
    rv1 = *(const ushort8*)(Vs + wid * 1024 + 512 + lane * 8);
    if (tid < 64) rmf = (Mg[tid] != 0) ? 0.f : MASKBIAS;
  }

  int cur = 0;
  for (int kt = 0; kt < NT_; ++kt) {
    // write staged regs -> buf[cur]
    *(ushort8*)(&Kb[cur][wid * 1024 + lane * 8])       = rk0;
    *(ushort8*)(&Kb[cur][wid * 1024 + 512 + lane * 8]) = rk1;
    *(ushort8*)(&Vb[cur][wid * 1024 + lane * 8])       = rv0;
    *(ushort8*)(&Vb[cur][wid * 1024 + 512 + lane * 8]) = rv1;
    if (tid < 64) mb[cur][tid] = rmf;

    // T14: issue next tile's global loads early
    if (kt + 1 < NT_) {
      const ushort* Ks = Kbase + (size_t)(kt + 1) * 4096;
      const ushort* Vs = Vbase + (size_t)(kt + 1) * 4096;
      rk0 = *(const ushort8*)(Ks + wid * 1024 + lane * 8);
      rk1 = *(const ushort8*)(Ks + wid * 1024 + 512 + lane * 8);
      rv0 = *(const ushort8*)(Vs + wid * 1024 + lane * 8);
      rv1 = *(const ushort8*)(Vs + wid * 1024 + 512 + lane * 8);
      if (tid < 64) rmf = (Mg[(kt + 1) * 64 + tid] != 0) ? 0.f : MASKBIAS;
    }
    __syncthreads();

    const ushort* Kc = Kb[cur];
    const ushort* Vc = Vb[cur];
    const float*  mc = mb[cur];

    // mask bias, doubles as MFMA C-init (row = k = 16t+4lg+r)
    f32x4 bt[4];
#pragma unroll
    for (int t = 0; t < 4; ++t) bt[t] = *(const f32x4*)(mc + 16 * t + 4 * lg);

    // ---- S^T = K Q^T, C-init = bias: lane holds S[k=16t+4lg+r][q=lr] ----
    f32x4 st[4][4];
    {
      bf16x8 kf[4];
#pragma unroll
      for (int t = 0; t < 4; ++t)
        kf[t] = *(const bf16x8*)(Kc + (16 * t + lr) * 64 + ((lg * 8) ^ ((lr & 7) << 3)));
      __builtin_amdgcn_s_setprio(1);
#pragma unroll
      for (int g = 0; g < 4; ++g)
#pragma unroll
        for (int t = 0; t < 4; ++t)
          st[g][t] = __builtin_amdgcn_mfma_f32_16x16x32_bf16(kf[t], qf[g][0], bt[t], 0, 0, 0);
      __builtin_amdgcn_s_setprio(0);
    }
    {
      bf16x8 kf[4];
#pragma unroll
      for (int t = 0; t < 4; ++t)
        kf[t] = *(const bf16x8*)(Kc + (16 * t + lr) * 64 + ((32 + lg * 8) ^ ((lr & 7) << 3)));
      __builtin_amdgcn_s_setprio(1);
#pragma unroll
      for (int g = 0; g < 4; ++g)
#pragma unroll
        for (int t = 0; t < 4; ++t)
          st[g][t] = __builtin_amdgcn_mfma_f32_16x16x32_bf16(kf[t], qf[g][1], st[g][t], 0, 0, 0);
      __builtin_amdgcn_s_setprio(0);
    }

    // ---- online softmax with defer-max (THR=8, exp2 domain) ----
    union PKU { uint32_t u[8]; bf16x8 v[2]; } pk[4];
#pragma unroll
    for (int g = 0; g < 4; ++g) {
      f32x4 s0 = st[g][0], s1 = st[g][1], s2 = st[g][2], s3 = st[g][3];
      float m0 = fmaxf(fmaxf(s0[0], s0[1]), fmaxf(s0[2], s0[3]));
      float m1 = fmaxf(fmaxf(s1[0], s1[1]), fmaxf(s1[2], s1[3]));
      float m2 = fmaxf(fmaxf(s2[0], s2[1]), fmaxf(s2[2], s2[3]));
      float m3 = fmaxf(fmaxf(s3[0], s3[1]), fmaxf(s3[2], s3[3]));
      float mt = fmaxf(fmaxf(m0, m1), fmaxf(m2, m3));
      mt = fmaxf(mt, __shfl_xor(mt, 16));
      mt = fmaxf(mt, __shfl_xor(mt, 32));

      if (!__all(mt - m_run[g] <= 8.0f)) {          // rescale path (rare)
        float mnew = fmaxf(m_run[g], mt);
        float fac  = __builtin_amdgcn_exp2f(m_run[g] - mnew);
        m_run[g] = mnew;
        l_run[g] *= fac;
        float fq[4];
#pragma unroll
        for (int r = 0; r < 4; ++r) fq[r] = __shfl(fac, 20 * lg + r);
#pragma unroll
        for (int dt = 0; dt < 4; ++dt)
#pragma unroll
          for (int r = 0; r < 4; ++r) o_acc[g][dt][r] *= fq[r];
      }
      const float mm = m_run[g];
      f32x4 p0, p1, p2, p3;
#pragma unroll
      for (int r = 0; r < 4; ++r) {
        p0[r] = __builtin_amdgcn_exp2f(s0[r] - mm);
        p1[r] = __builtin_amdgcn_exp2f(s1[r] - mm);
        p2[r] = __builtin_amdgcn_exp2f(s2[r] - mm);
        p3[r] = __builtin_amdgcn_exp2f(s3[r] - mm);
      }
      float sum = ((p0[0]+p0[1])+(p0[2]+p0[3])) + ((p1[0]+p1[1])+(p1[2]+p1[3]))
                + ((p2[0]+p2[1])+(p2[2]+p2[3])) + ((p3[0]+p3[1])+(p3[2]+p3[3]));
      sum += __shfl_xor(sum, 16);
      sum += __shfl_xor(sum, 32);
      l_run[g] += sum;

      pk[g].u[0] = pkbf(p0[0], p0[1]); pk[g].u[1] = pkbf(p0[2], p0[3]);
      pk[g].u[2] = pkbf(p1[0], p1[1]); pk[g].u[3] = pkbf(p1[2], p1[3]);
      pk[g].u[4] = pkbf(p2[0], p2[1]); pk[g].u[5] = pkbf(p2[2], p2[3]);
      pk[g].u[6] = pkbf(p3[0], p3[1]); pk[g].u[7] = pkbf(p3[2], p3[3]);
    }

    // ---- O += P V : A-frag = lane-local pk words (k-order matches Vtp perm) ----
    __builtin_amdgcn_s_setprio(1);
#pragma unroll
    for (int c = 0; c < 2; ++c)
#pragma unroll
      for (int dt = 0; dt < 4; ++dt) {
        bf16x8 vb = *(const bf16x8*)(Vc + (16 * dt + lr) * 64 + ((c * 32 + lg * 8) ^ ((lr & 7) << 3)));
#pragma unroll
        for (int g = 0; g < 4; ++g)
          o_acc[g][dt] = __builtin_amdgcn_mfma_f32_16x16x32_bf16(pk[g].v[c], vb, o_acc[g][dt], 0, 0, 0);
      }
    __builtin_amdgcn_s_setprio(0);
    cur ^= 1;
  }

  // ---- epilogue: O / l ----
#pragma unroll
  for (int g = 0; g < 4; ++g) {
    float linv[4];
#pragma unroll
    for (int r = 0; r < 4; ++r) {
      float lq = __shfl(l_run[g], 20 * lg + r);
      linv[r] = 1.0f / lq;
    }
#pragma unroll
    for (int dt = 0; dt < 4; ++dt)
#pragma unroll
      for (int r = 0; r < 4; ++r) {
        int row = qbase + g * 16 + 4 * lg + r;
        Og[(size_t)row * D_ + dt * 16 + lr] = o_acc[g][dt][r] * linv[r];
      }
  }
}

extern "C" void kernel_launch(void* const* d_in, const int* in_sizes, int n_in,
                              void* d_out, int out_size, void* d_ws, size_t ws_size,
                              hipStream_t stream) {
  const float* Q = (const float*)d_in[0];
  const float* K = (const float*)d_in[1];
  const float* V = (const float*)d_in[2];
  const int*   M = (const int*)d_in[3];
  float*       O = (float*)d_out;

  const size_t elems = (size_t)BH_ * L_ * D_;   // 8,388,608
  ushort* Kp  = (ushort*)d_ws;
  ushort* Vtp = Kp + elems;
  prep_kv<<<dim3(BH_ * NT_), dim3(256), 0, stream>>>(K, V, Kp, Vtp);
  attn_fwd3<<<dim3(512), dim3(256), 0, stream>>>(Q, M, Kp, Vtp, O);
}